// Round 1
// 512.174 us; speedup vs baseline: 1.0526x; 1.0526x over previous
//
#include <hip/hip_runtime.h>
#include <math.h>

#define RES 64
#define IN_HW 56
#define K_KP 17
#define N_ROWS 4096
#define N_CLS 91
#define R_ROIS 1024
#define SMOOTH_BETA (1.0f / 9.0f)

#define KP_BLOCKS (R_ROIS * K_KP)          /* 17408 */
#define LOSS_BLOCKS 256                    /* 16 rows per block */
#define MASK_START (KP_BLOCKS + LOSS_BLOCKS)
#define TOTAL_BLOCKS (MASK_START + R_ROIS) /* 18688 */

// Output layout (fp32 flat):
//   [0]                      cls_loss
//   [1]                      box_loss
//   [2 .. 2+52224)           xy_preds  (1024,17,3)
//   [52226 .. 52226+17408)   end_scores (1024,17)
//   [69634 .. 69634+802816)  mask_prob (1024,1,28,28)

__device__ __forceinline__ float keys_cubic(float x) {
    x = fabsf(x);
    if (x < 1.f) return ((1.5f * x - 2.5f) * x) * x + 1.f;
    if (x < 2.f) return ((-0.5f * x + 2.5f) * x - 4.f) * x + 2.f;
    return 0.f;
}

// floor((7*o - 0.5)/8) == (7*o - 1) >> 3 for integer o >= 0 (arith shift)
__device__ __forceinline__ int fl_of(int o) { return (7 * o - 1) >> 3; }

// One launch for everything:
//   blocks [0, 17408)        : keypoint bicubic 56->64 + argmax (1 block per (r,k))
//   blocks [17408, 17664)    : fastrcnn losses, 16 rows/block, partials -> ws
//   blocks [17664, 18688)    : mask sigmoid gather (1 block per roi)
// Small block ranges are placed LAST so they execute during the kp tail drain.
__global__ __launch_bounds__(256) void fused_kernel(
    const float* __restrict__ maps, const float* __restrict__ rois,
    const float* __restrict__ logits, const float* __restrict__ boxreg,
    const int* __restrict__ labels, const float* __restrict__ tgt,
    const float* __restrict__ ml, const int* __restrict__ mlab,
    float* __restrict__ out, float* __restrict__ ws)
{
    __shared__ float  sm_in[IN_HW * IN_HW];   // 3136 f
    __shared__ float  sm_tmp[IN_HW * RES];    // 3584 f
    __shared__ float4 s_w4[RES];              // normalized 4-tap weights per output idx
    __shared__ float  s_red_v[4];
    __shared__ int    s_red_i[4];

    const int bid = blockIdx.x;
    const int tid = threadIdx.x;
    const int wv = tid >> 6, ln = tid & 63;

    if (bid < KP_BLOCKS) {
        // ---------------- keypoints: bicubic 56->64 + argmax ----------------
        const int map_id = bid;               // r*17 + k

        // stage 56x56 map into LDS (float4, coalesced, 16B-aligned)
        {
            const float4* src = (const float4*)(maps + (size_t)map_id * (IN_HW * IN_HW));
            float4* dst = (float4*)sm_in;
            for (int i = tid; i < (IN_HW * IN_HW) / 4; i += 256) dst[i] = src[i];
        }

        // bicubic weights (JAX: half-pixel centers, Keys a=-0.5, OOR taps dropped + renorm)
        if (tid < RES) {
            float s = (tid + 0.5f) * (56.f / 64.f) - 0.5f;   // exact in fp32
            int fl = (int)floorf(s);
            float w[4]; float wsum = 0.f;
            #pragma unroll
            for (int t = 0; t < 4; ++t) {
                int i = fl - 1 + t;
                float wv2 = keys_cubic(s - (float)i);
                if (i < 0 || i >= IN_HW) wv2 = 0.f;
                w[t] = wv2; wsum += wv2;
            }
            float inv = 1.f / wsum;
            s_w4[tid] = make_float4(w[0] * inv, w[1] * inv, w[2] * inv, w[3] * inv);
        }
        __syncthreads();

        // horizontal pass: wave shares y, lanes span ox; weights/indices hoisted
        {
            const int ox = ln;
            const int fl = fl_of(ox);                         // -1..55
            const int i0 = max(fl - 1, 0);
            const int i1 = max(fl, 0);
            const int i2 = min(fl + 1, IN_HW - 1);
            const int i3 = min(fl + 2, IN_HW - 1);
            const float4 w = s_w4[ox];
            for (int y = wv; y < IN_HW; y += 4) {
                const float* row = sm_in + y * IN_HW;
                sm_tmp[y * RES + ox] = w.x * row[i0] + w.y * row[i1]
                                     + w.z * row[i2] + w.w * row[i3];
            }
        }
        __syncthreads();

        // vertical pass: lane = ox, 16 consecutive oy per wave; register sliding window
        float best = -INFINITY; int bidx = 0;
        {
            const int ox = ln;
            const int oy0 = wv * 16;
            int fl = fl_of(oy0);
            #define CLAMP_ROW(i) (min(max((i), 0), IN_HW - 1))
            float r0 = sm_tmp[CLAMP_ROW(fl - 1) * RES + ox];
            float r1 = sm_tmp[CLAMP_ROW(fl    ) * RES + ox];
            float r2 = sm_tmp[CLAMP_ROW(fl + 1) * RES + ox];
            float r3 = sm_tmp[CLAMP_ROW(fl + 2) * RES + ox];
            #pragma unroll
            for (int k = 0; k < 16; ++k) {
                const int oy = oy0 + k;
                const float4 w = s_w4[oy];                    // broadcast b128
                float v = w.x * r0 + w.y * r1 + w.z * r2 + w.w * r3;
                if (v > best) { best = v; bidx = oy * RES + ox; }
                if (k < 15) {
                    int nfl = fl_of(oy + 1);                  // wave-uniform branch
                    if (nfl != fl) {
                        r0 = r1; r1 = r2; r2 = r3;
                        r3 = sm_tmp[CLAMP_ROW(nfl + 2) * RES + ox];
                        fl = nfl;
                    }
                }
            }
            #undef CLAMP_ROW
        }
        #pragma unroll
        for (int off = 32; off; off >>= 1) {
            float ov = __shfl_down(best, off);
            int   oi = __shfl_down(bidx, off);
            if (ov > best || (ov == best && oi < bidx)) { best = ov; bidx = oi; }
        }
        if (ln == 0) { s_red_v[wv] = best; s_red_i[wv] = bidx; }
        __syncthreads();
        if (tid == 0) {
            float bv = s_red_v[0]; int bi = s_red_i[0];
            #pragma unroll
            for (int w = 1; w < 4; ++w) {
                float v = s_red_v[w]; int i2 = s_red_i[w];
                if (v > bv || (v == bv && i2 < bi)) { bv = v; bi = i2; }
            }
            const int r = map_id / K_KP;
            const float x0 = rois[r * 4 + 0], y0r = rois[r * 4 + 1];
            const float x1 = rois[r * 4 + 2], y1r = rois[r * 4 + 3];
            const float wdt = fmaxf(x1 - x0, 1.f), hgt = fmaxf(y1r - y0r, 1.f);
            const float wc = wdt * (1.f / 64.f), hc = hgt * (1.f / 64.f);
            const int xi = bi & 63, yi = bi >> 6;
            float* xyp = out + 2 + (size_t)map_id * 3;
            xyp[0] = ((float)xi + 0.5f) * wc + x0;
            xyp[1] = ((float)yi + 0.5f) * hc + y0r;
            xyp[2] = 1.f;
            out[52226 + map_id] = bv;
        }
        return;
    }

    if (bid >= MASK_START) {
        // ------------- mask: gather selected class, sigmoid, write -------------
        const int r = bid - MASK_START;
        const int lbl = mlab[r];
        const float2* src = (const float2*)(ml + ((size_t)r * N_CLS + lbl) * 784);
        float2* dst = (float2*)(out + 69634 + (size_t)r * 784);
        for (int i = tid; i < 392; i += 256) {
            float2 v = src[i];
            float2 o;
            o.x = 1.f / (1.f + expf(-v.x));
            o.y = 1.f / (1.f + expf(-v.y));
            dst[i] = o;
        }
        return;
    }

    // ---------------- losses: 16 rows/block, deterministic partials to ws ----------------
    const int b = bid - KP_BLOCKS;            // 0..255
    float csum = 0.f, bsum = 0.f;
    #pragma unroll
    for (int i = 0; i < 4; ++i) {
        const int row = b * 16 + wv * 4 + i;
        const float* lr = logits + (size_t)row * N_CLS;
        float a  = (ln < N_CLS) ? lr[ln] : -INFINITY;
        float a2 = (ln + 64 < N_CLS) ? lr[ln + 64] : -INFINITY;
        float m = fmaxf(a, a2);
        #pragma unroll
        for (int off = 32; off; off >>= 1) m = fmaxf(m, __shfl_down(m, off));
        m = __shfl(m, 0);
        float e = 0.f;
        if (ln < N_CLS) e += expf(a - m);
        if (ln + 64 < N_CLS) e += expf(a2 - m);
        #pragma unroll
        for (int off = 32; off; off >>= 1) e += __shfl_down(e, off);
        if (ln == 0) {
            float lsm = m + logf(e);
            int lbl = labels[row];
            const float* sel = boxreg + (size_t)row * (4 * N_CLS) + lbl * 4;
            const float* tg = tgt + (size_t)row * 4;
            float s = 0.f;
            #pragma unroll
            for (int j = 0; j < 4; ++j) {
                float d = sel[j] - tg[j];
                float ad = fabsf(d);
                s += (ad < SMOOTH_BETA) ? (0.5f * d * d / SMOOTH_BETA)
                                        : (ad - 0.5f * SMOOTH_BETA);
            }
            csum += lsm - lr[lbl];
            if (lbl > 0) bsum += s;
        }
    }
    if (ln == 0) { s_red_v[wv] = csum; s_red_i[wv] = __float_as_int(bsum); }
    __syncthreads();
    if (tid == 0) {
        float c  = s_red_v[0] + s_red_v[1] + s_red_v[2] + s_red_v[3];
        float bx = __int_as_float(s_red_i[0]) + __int_as_float(s_red_i[1])
                 + __int_as_float(s_red_i[2]) + __int_as_float(s_red_i[3]);
        ws[b * 2]     = c;
        ws[b * 2 + 1] = bx;
    }
}

// Tiny finisher: reduce 256 loss partial pairs -> out[0], out[1]. Runs after
// fused_kernel via stream ordering. Writes directly (no memset/atomics needed).
__global__ __launch_bounds__(256) void loss_finish(
    const float* __restrict__ ws, float* __restrict__ out)
{
    __shared__ float s_c[4], s_b[4];
    const int tid = threadIdx.x, wv = tid >> 6, ln = tid & 63;
    float c = ws[tid * 2];
    float b = ws[tid * 2 + 1];
    #pragma unroll
    for (int off = 32; off; off >>= 1) {
        c += __shfl_down(c, off);
        b += __shfl_down(b, off);
    }
    if (ln == 0) { s_c[wv] = c; s_b[wv] = b; }
    __syncthreads();
    if (tid == 0) {
        float cc = s_c[0] + s_c[1] + s_c[2] + s_c[3];
        float bb = s_b[0] + s_b[1] + s_b[2] + s_b[3];
        out[0] = cc * (1.f / (float)N_ROWS);
        out[1] = bb * (1.f / (float)N_ROWS);
    }
}

extern "C" void kernel_launch(void* const* d_in, const int* in_sizes, int n_in,
                              void* d_out, int out_size, void* d_ws, size_t ws_size,
                              hipStream_t stream) {
    const float* class_logits = (const float*)d_in[0];
    const float* box_regression = (const float*)d_in[1];
    const int*   labels = (const int*)d_in[2];
    const float* regression_targets = (const float*)d_in[3];
    const float* kp_maps = (const float*)d_in[4];
    const float* kp_rois = (const float*)d_in[5];
    const float* mask_logits = (const float*)d_in[6];
    const int*   mask_labels = (const int*)d_in[7];
    float* out = (float*)d_out;
    float* ws  = (float*)d_ws;

    fused_kernel<<<TOTAL_BLOCKS, 256, 0, stream>>>(
        kp_maps, kp_rois, class_logits, box_regression, labels,
        regression_targets, mask_logits, mask_labels, out, ws);
    loss_finish<<<1, 256, 0, stream>>>(ws, out);
}

// Round 2
// 499.061 us; speedup vs baseline: 1.0803x; 1.0263x over previous
//
#include <hip/hip_runtime.h>
#include <math.h>
#include <stdint.h>

#define RES 64
#define IN_HW 56
#define K_KP 17
#define N_ROWS 4096
#define N_CLS 91
#define R_ROIS 1024
#define SMOOTH_BETA (1.0f / 9.0f)

#define KP_BLOCKS (R_ROIS * K_KP)          /* 17408 */
#define LOSS_BLOCKS 256                    /* 16 rows per block */
#define MASK_START (KP_BLOCKS + LOSS_BLOCKS)
#define TOTAL_BLOCKS (MASK_START + R_ROIS) /* 18688 */

// Output layout (fp32 flat):
//   [0]                      cls_loss
//   [1]                      box_loss
//   [2 .. 2+52224)           xy_preds  (1024,17,3)
//   [52226 .. 52226+17408)   end_scores (1024,17)
//   [69634 .. 69634+802816)  mask_prob (1024,1,28,28)

__device__ __forceinline__ float keys_cubic(float x) {
    x = fabsf(x);
    if (x < 1.f) return ((1.5f * x - 2.5f) * x) * x + 1.f;
    if (x < 2.f) return ((-0.5f * x + 2.5f) * x - 4.f) * x + 2.f;
    return 0.f;
}

// floor((7*o - 0.5)/8) == (7*o - 1) >> 3 for integer o >= 0 (arith shift)
__device__ __forceinline__ int fl_of(int o) { return (7 * o - 1) >> 3; }
// clamped 4-tap base row/col for output index o (always in [0, 52])
__device__ __forceinline__ int base_of(int o) {
    return min(max(fl_of(o) - 1, 0), IN_HW - 4);
}

#define GLB_AS __attribute__((address_space(1)))
#define LDS_AS __attribute__((address_space(3)))
__device__ __forceinline__ void gload_lds16(const void* g, void* l) {
    __builtin_amdgcn_global_load_lds((const GLB_AS uint32_t*)g,
                                     (LDS_AS uint32_t*)l, 16, 0, 0);
}
__device__ __forceinline__ void gload_lds4(const void* g, void* l) {
    __builtin_amdgcn_global_load_lds((const GLB_AS uint32_t*)g,
                                     (LDS_AS uint32_t*)l, 4, 0, 0);
}

// One launch for everything:
//   blocks [0, 17408)        : keypoint bicubic 56->64 + argmax (1 block per (r,k))
//   blocks [17408, 17664)    : fastrcnn losses, 16 rows/block, partials -> ws
//   blocks [17664, 18688)    : mask sigmoid gather (1 block per roi)
__global__ __launch_bounds__(256) void fused_kernel(
    const float* __restrict__ maps, const float* __restrict__ rois,
    const float* __restrict__ logits, const float* __restrict__ boxreg,
    const int* __restrict__ labels, const float* __restrict__ tgt,
    const float* __restrict__ ml, const int* __restrict__ mlab,
    float* __restrict__ out, float* __restrict__ ws)
{
    __shared__ float  sm_in[IN_HW * IN_HW];   // 3136 f = 12544 B
    __shared__ float  sm_tmp[IN_HW * RES];    // 3584 f = 14336 B
    __shared__ float4 s_w4[RES];              // base-aligned normalized 4-tap weights
    __shared__ float  s_red_v[4];
    __shared__ int    s_red_i[4];

    const int bid = blockIdx.x;
    const int tid = threadIdx.x;
    const int wv = tid >> 6, ln = tid & 63;

    if (bid < KP_BLOCKS) {
        // ---------------- keypoints: bicubic 56->64 + argmax ----------------
        const int map_id = bid;               // r*17 + k

        // stage 56x56 map directly into LDS: 12 wave-instructions of 1 KiB
        // (wave-uniform LDS base + lane*16, linear layout) + 256 B tail.
        {
            const char* gb = (const char*)(maps + (size_t)map_id * (IN_HW * IN_HW));
            char* lb = (char*)sm_in;
            #pragma unroll
            for (int j = 0; j < 3; ++j) {
                const int o = ((j * 4 + wv) * 64 + ln) * 16;
                gload_lds16(gb + o, lb + o);
            }
            if (wv == 0) {
                const int o = 12288 + ln * 4;
                gload_lds4(gb + o, lb + o);
            }
        }

        // bicubic weights, BASE-ALIGNED (JAX: half-pixel centers, Keys a=-0.5,
        // OOR taps dropped + renorm). Output o reads inputs base..base+3 with
        // weights s_w4[o]; base = clamp(fl-1, 0, 52). Exactly equivalent to the
        // clamped-index form since OOR tap weights are zero.
        if (tid < RES) {
            float s = (tid + 0.5f) * (56.f / 64.f) - 0.5f;   // exact in fp32
            int fl = (int)floorf(s);
            float w[4]; float wsum = 0.f;
            #pragma unroll
            for (int t = 0; t < 4; ++t) {
                int i = fl - 1 + t;
                float wt = keys_cubic(s - (float)i);
                if (i < 0 || i >= IN_HW) wt = 0.f;
                w[t] = wt; wsum += wt;
            }
            const int base = min(max(fl - 1, 0), IN_HW - 4);
            const int shift = (fl - 1) - base;               // in [-2, 2]
            float wa[4];
            #pragma unroll
            for (int j = 0; j < 4; ++j) {
                int t = j - shift;
                wa[j] = (t >= 0 && t < 4) ? w[t] : 0.f;
            }
            float inv = 1.f / wsum;                          // sum preserved by shift
            s_w4[tid] = make_float4(wa[0] * inv, wa[1] * inv, wa[2] * inv, wa[3] * inv);
        }
        __syncthreads();

        // horizontal pass: wave shares y, lanes span ox. Taps are 4 CONTIGUOUS
        // floats at a common base -> compiler merges into 2x ds_read2_b32.
        {
            const int ox = ln;
            const int base = base_of(ox);
            const float4 w = s_w4[ox];
            for (int y = wv; y < IN_HW; y += 4) {
                const float* p = sm_in + y * IN_HW + base;
                float t0 = p[0], t1 = p[1], t2 = p[2], t3 = p[3];
                sm_tmp[y * RES + ox] = w.x * t0 + w.y * t1 + w.z * t2 + w.w * t3;
            }
        }
        __syncthreads();

        // vertical pass: lane = ox, 16 consecutive oy per wave; register sliding
        // window over 4 tmp rows at stride 64 dwords (ds_read2_b32 pairs on init).
        float best = -INFINITY; int bidx = 0;
        {
            const int ox = ln;
            const int oy0 = wv * 16;
            int base = base_of(oy0);
            const float* q = sm_tmp + base * RES + ox;
            float r0 = q[0], r1 = q[64], r2 = q[128], r3 = q[192];
            #pragma unroll
            for (int k = 0; k < 16; ++k) {
                const int oy = oy0 + k;
                const float4 w = s_w4[oy];                    // broadcast b128
                float v = w.x * r0 + w.y * r1 + w.z * r2 + w.w * r3;
                if (v > best) { best = v; bidx = oy * RES + ox; }
                if (k < 15) {
                    const int nb = base_of(oy + 1);           // wave-uniform
                    if (nb != base) {
                        r0 = r1; r1 = r2; r2 = r3;
                        r3 = sm_tmp[(nb + 3) * RES + ox];
                        base = nb;
                    }
                }
            }
        }
        #pragma unroll
        for (int off = 32; off; off >>= 1) {
            float ov = __shfl_down(best, off);
            int   oi = __shfl_down(bidx, off);
            if (ov > best || (ov == best && oi < bidx)) { best = ov; bidx = oi; }
        }
        if (ln == 0) { s_red_v[wv] = best; s_red_i[wv] = bidx; }
        __syncthreads();
        if (tid == 0) {
            float bv = s_red_v[0]; int bi = s_red_i[0];
            #pragma unroll
            for (int w = 1; w < 4; ++w) {
                float v = s_red_v[w]; int i2 = s_red_i[w];
                if (v > bv || (v == bv && i2 < bi)) { bv = v; bi = i2; }
            }
            const int r = map_id / K_KP;
            const float x0 = rois[r * 4 + 0], y0r = rois[r * 4 + 1];
            const float x1 = rois[r * 4 + 2], y1r = rois[r * 4 + 3];
            const float wdt = fmaxf(x1 - x0, 1.f), hgt = fmaxf(y1r - y0r, 1.f);
            const float wc = wdt * (1.f / 64.f), hc = hgt * (1.f / 64.f);
            const int xi = bi & 63, yi = bi >> 6;
            float* xyp = out + 2 + (size_t)map_id * 3;
            xyp[0] = ((float)xi + 0.5f) * wc + x0;
            xyp[1] = ((float)yi + 0.5f) * hc + y0r;
            xyp[2] = 1.f;
            out[52226 + map_id] = bv;
        }
        return;
    }

    if (bid >= MASK_START) {
        // ------------- mask: gather selected class, sigmoid, write -------------
        const int r = bid - MASK_START;
        const int lbl = mlab[r];
        const float2* src = (const float2*)(ml + ((size_t)r * N_CLS + lbl) * 784);
        float2* dst = (float2*)(out + 69634 + (size_t)r * 784);
        for (int i = tid; i < 392; i += 256) {
            float2 v = src[i];
            float2 o;
            o.x = 1.f / (1.f + expf(-v.x));
            o.y = 1.f / (1.f + expf(-v.y));
            dst[i] = o;
        }
        return;
    }

    // ---------------- losses: 16 rows/block, deterministic partials to ws ----------------
    const int b = bid - KP_BLOCKS;            // 0..255
    float csum = 0.f, bsum = 0.f;
    #pragma unroll
    for (int i = 0; i < 4; ++i) {
        const int row = b * 16 + wv * 4 + i;
        const float* lr = logits + (size_t)row * N_CLS;
        float a  = (ln < N_CLS) ? lr[ln] : -INFINITY;
        float a2 = (ln + 64 < N_CLS) ? lr[ln + 64] : -INFINITY;
        float m = fmaxf(a, a2);
        #pragma unroll
        for (int off = 32; off; off >>= 1) m = fmaxf(m, __shfl_down(m, off));
        m = __shfl(m, 0);
        float e = 0.f;
        if (ln < N_CLS) e += expf(a - m);
        if (ln + 64 < N_CLS) e += expf(a2 - m);
        #pragma unroll
        for (int off = 32; off; off >>= 1) e += __shfl_down(e, off);
        if (ln == 0) {
            float lsm = m + logf(e);
            int lbl = labels[row];
            const float* sel = boxreg + (size_t)row * (4 * N_CLS) + lbl * 4;
            const float* tg = tgt + (size_t)row * 4;
            float s = 0.f;
            #pragma unroll
            for (int j = 0; j < 4; ++j) {
                float d = sel[j] - tg[j];
                float ad = fabsf(d);
                s += (ad < SMOOTH_BETA) ? (0.5f * d * d / SMOOTH_BETA)
                                        : (ad - 0.5f * SMOOTH_BETA);
            }
            csum += lsm - lr[lbl];
            if (lbl > 0) bsum += s;
        }
    }
    if (ln == 0) { s_red_v[wv] = csum; s_red_i[wv] = __float_as_int(bsum); }
    __syncthreads();
    if (tid == 0) {
        float c  = s_red_v[0] + s_red_v[1] + s_red_v[2] + s_red_v[3];
        float bx = __int_as_float(s_red_i[0]) + __int_as_float(s_red_i[1])
                 + __int_as_float(s_red_i[2]) + __int_as_float(s_red_i[3]);
        ws[b * 2]     = c;
        ws[b * 2 + 1] = bx;
    }
}

// Tiny finisher: reduce 256 loss partial pairs -> out[0], out[1].
__global__ __launch_bounds__(256) void loss_finish(
    const float* __restrict__ ws, float* __restrict__ out)
{
    __shared__ float s_c[4], s_b[4];
    const int tid = threadIdx.x, wv = tid >> 6, ln = tid & 63;
    float c = ws[tid * 2];
    float b = ws[tid * 2 + 1];
    #pragma unroll
    for (int off = 32; off; off >>= 1) {
        c += __shfl_down(c, off);
        b += __shfl_down(b, off);
    }
    if (ln == 0) { s_c[wv] = c; s_b[wv] = b; }
    __syncthreads();
    if (tid == 0) {
        float cc = s_c[0] + s_c[1] + s_c[2] + s_c[3];
        float bb = s_b[0] + s_b[1] + s_b[2] + s_b[3];
        out[0] = cc * (1.f / (float)N_ROWS);
        out[1] = bb * (1.f / (float)N_ROWS);
    }
}

extern "C" void kernel_launch(void* const* d_in, const int* in_sizes, int n_in,
                              void* d_out, int out_size, void* d_ws, size_t ws_size,
                              hipStream_t stream) {
    const float* class_logits = (const float*)d_in[0];
    const float* box_regression = (const float*)d_in[1];
    const int*   labels = (const int*)d_in[2];
    const float* regression_targets = (const float*)d_in[3];
    const float* kp_maps = (const float*)d_in[4];
    const float* kp_rois = (const float*)d_in[5];
    const float* mask_logits = (const float*)d_in[6];
    const int*   mask_labels = (const int*)d_in[7];
    float* out = (float*)d_out;
    float* ws  = (float*)d_ws;

    fused_kernel<<<TOTAL_BLOCKS, 256, 0, stream>>>(
        kp_maps, kp_rois, class_logits, box_regression, labels,
        regression_targets, mask_logits, mask_labels, out, ws);
    loss_finish<<<1, 256, 0, stream>>>(ws, out);
}

// Round 4
// 489.310 us; speedup vs baseline: 1.1018x; 1.0199x over previous
//
#include <hip/hip_runtime.h>
#include <math.h>
#include <stdint.h>

#define RES 64
#define IN_HW 56
#define K_KP 17
#define N_ROWS 4096
#define N_CLS 91
#define R_ROIS 1024
#define SMOOTH_BETA (1.0f / 9.0f)

#define KP_BLOCKS (R_ROIS * K_KP)          /* 17408 */
#define LOSS_BLOCKS 256                    /* 16 rows per block */
#define MASK_START (KP_BLOCKS + LOSS_BLOCKS)
#define TOTAL_BLOCKS (MASK_START + R_ROIS) /* 18688 */

// Output layout (fp32 flat):
//   [0]                      cls_loss
//   [1]                      box_loss
//   [2 .. 2+52224)           xy_preds  (1024,17,3)
//   [52226 .. 52226+17408)   end_scores (1024,17)
//   [69634 .. 69634+802816)  mask_prob (1024,1,28,28)

__device__ __forceinline__ float keys_cubic(float x) {
    x = fabsf(x);
    if (x < 1.f) return ((1.5f * x - 2.5f) * x) * x + 1.f;
    if (x < 2.f) return ((-0.5f * x + 2.5f) * x - 4.f) * x + 2.f;
    return 0.f;
}

// floor((7*o - 0.5)/8) == (7*o - 1) >> 3 for integer o >= 0 (arith shift)
__device__ __forceinline__ int fl_of(int o) { return (7 * o - 1) >> 3; }
// clamped 4-tap base row/col for output index o (always in [0, 52])
__device__ __forceinline__ int base_of(int o) {
    return min(max(fl_of(o) - 1, 0), IN_HW - 4);
}

#define GLB_AS __attribute__((address_space(1)))
#define LDS_AS __attribute__((address_space(3)))
__device__ __forceinline__ void gload_lds16(const void* g, void* l) {
    __builtin_amdgcn_global_load_lds((const GLB_AS uint32_t*)g,
                                     (LDS_AS uint32_t*)l, 16, 0, 0);
}
__device__ __forceinline__ void gload_lds4(const void* g, void* l) {
    __builtin_amdgcn_global_load_lds((const GLB_AS uint32_t*)g,
                                     (LDS_AS uint32_t*)l, 4, 0, 0);
}

// One launch for everything:
//   blocks [0, 17408)        : keypoint bicubic 56->64 + argmax (1 block per (r,k))
//   blocks [17408, 17664)    : fastrcnn losses, 16 rows/block, partials -> ws
//   blocks [17664, 18688)    : mask sigmoid gather (1 block per roi)
__global__ __launch_bounds__(256) void fused_kernel(
    const float* __restrict__ maps, const float* __restrict__ rois,
    const float* __restrict__ logits, const float* __restrict__ boxreg,
    const int* __restrict__ labels, const float* __restrict__ tgt,
    const float* __restrict__ ml, const int* __restrict__ mlab,
    float* __restrict__ out, float* __restrict__ ws)
{
    __shared__ float  sm_in[IN_HW * IN_HW];   // 3136 f = 12544 B
    __shared__ float4 s_w4[RES];              // base-aligned normalized 4-tap weights
    __shared__ float  s_red_v[4];
    __shared__ int    s_red_i[4];

    const int bid = blockIdx.x;
    const int tid = threadIdx.x;
    const int wv = tid >> 6, ln = tid & 63;

    if (bid < KP_BLOCKS) {
        // ---------------- keypoints: bicubic 56->64 + argmax, FUSED H+V ----------------
        const int map_id = bid;               // r*17 + k

        // stage 56x56 map directly into LDS (wave-uniform base + lane*16, linear)
        {
            const char* gb = (const char*)(maps + (size_t)map_id * (IN_HW * IN_HW));
            char* lb = (char*)sm_in;
            #pragma unroll
            for (int j = 0; j < 3; ++j) {
                const int o = ((j * 4 + wv) * 64 + ln) * 16;
                gload_lds16(gb + o, lb + o);
            }
            if (wv == 0) {
                const int o = 12288 + ln * 4;
                gload_lds4(gb + o, lb + o);
            }
        }

        // bicubic weights, BASE-ALIGNED (JAX: half-pixel centers, Keys a=-0.5,
        // OOR taps dropped + renorm). Output o reads inputs base..base+3 with
        // weights s_w4[o]; base = clamp(fl-1, 0, 52). OOR tap weights are zero,
        // so the shifted form is exactly the clamped-index form.
        if (tid < RES) {
            float s = (tid + 0.5f) * (56.f / 64.f) - 0.5f;   // exact in fp32
            int fl = (int)floorf(s);
            float w[4]; float wsum = 0.f;
            #pragma unroll
            for (int t = 0; t < 4; ++t) {
                int i = fl - 1 + t;
                float wt = keys_cubic(s - (float)i);
                if (i < 0 || i >= IN_HW) wt = 0.f;
                w[t] = wt; wsum += wt;
            }
            const int base = min(max(fl - 1, 0), IN_HW - 4);
            const int shift = (fl - 1) - base;               // in [-2, 2]
            float wa[4];
            #pragma unroll
            for (int j = 0; j < 4; ++j) {
                int t = j - shift;
                wa[j] = (t >= 0 && t < 4) ? w[t] : 0.f;
            }
            float inv = 1.f / wsum;                          // sum preserved by shift
            s_w4[tid] = make_float4(wa[0] * inv, wa[1] * inv, wa[2] * inv, wa[3] * inv);
        }
        __syncthreads();

        // Fused pass: lane = ox, wave owns 16 consecutive oy. The 4-row vertical
        // sliding window is filled by computing horizontal-pass rows ON DEMAND
        // from sm_in (2x ds_read2_b32 + 4 FMA each) -- no sm_tmp round-trip.
        float best = -INFINITY; int bidx = 0;
        {
            const int ox = ln;
            const int hbase = base_of(ox);                   // per-lane, hoisted
            const float4 hw = s_w4[ox];
            const float* hp = sm_in + hbase;

            auto hrow = [&](int yy) -> float {
                const float* p = hp + yy * IN_HW;
                return hw.x * p[0] + hw.y * p[1] + hw.z * p[2] + hw.w * p[3];
            };

            const int oy0 = wv * 16;
            int base = base_of(oy0);
            float r0 = hrow(base);
            float r1 = hrow(base + 1);
            float r2 = hrow(base + 2);
            float r3 = hrow(base + 3);
            #pragma unroll
            for (int k = 0; k < 16; ++k) {
                const int oy = oy0 + k;
                const float4 w = s_w4[oy];                    // wave-uniform broadcast
                float v = w.x * r0 + w.y * r1 + w.z * r2 + w.w * r3;
                if (v > best) { best = v; bidx = oy * RES + ox; }
                if (k < 15) {
                    const int nb = base_of(oy + 1);           // wave-uniform
                    if (nb != base) {
                        r0 = r1; r1 = r2; r2 = r3;
                        r3 = hrow(nb + 3);
                        base = nb;
                    }
                }
            }
        }
        #pragma unroll
        for (int off = 32; off; off >>= 1) {
            float ov = __shfl_down(best, off);
            int   oi = __shfl_down(bidx, off);
            if (ov > best || (ov == best && oi < bidx)) { best = ov; bidx = oi; }
        }
        if (ln == 0) { s_red_v[wv] = best; s_red_i[wv] = bidx; }
        __syncthreads();
        if (tid == 0) {
            float bv = s_red_v[0]; int bi = s_red_i[0];
            #pragma unroll
            for (int w = 1; w < 4; ++w) {
                float v = s_red_v[w]; int i2 = s_red_i[w];
                if (v > bv || (v == bv && i2 < bi)) { bv = v; bi = i2; }
            }
            const int r = map_id / K_KP;
            const float x0 = rois[r * 4 + 0], y0r = rois[r * 4 + 1];
            const float x1 = rois[r * 4 + 2], y1r = rois[r * 4 + 3];
            const float wdt = fmaxf(x1 - x0, 1.f), hgt = fmaxf(y1r - y0r, 1.f);
            const float wc = wdt * (1.f / 64.f), hc = hgt * (1.f / 64.f);
            const int xi = bi & 63, yi = bi >> 6;
            float* xyp = out + 2 + (size_t)map_id * 3;
            xyp[0] = ((float)xi + 0.5f) * wc + x0;
            xyp[1] = ((float)yi + 0.5f) * hc + y0r;
            xyp[2] = 1.f;
            out[52226 + map_id] = bv;
        }
        return;
    }

    if (bid >= MASK_START) {
        // ------------- mask: gather selected class, sigmoid, write -------------
        const int r = bid - MASK_START;
        const int lbl = mlab[r];
        const float2* src = (const float2*)(ml + ((size_t)r * N_CLS + lbl) * 784);
        float2* dst = (float2*)(out + 69634 + (size_t)r * 784);
        for (int i = tid; i < 392; i += 256) {
            float2 v = src[i];
            float2 o;
            o.x = 1.f / (1.f + expf(-v.x));
            o.y = 1.f / (1.f + expf(-v.y));
            dst[i] = o;
        }
        return;
    }

    // ---------------- losses: 16 rows/block, deterministic partials to ws ----------------
    const int b = bid - KP_BLOCKS;            // 0..255
    float csum = 0.f, bsum = 0.f;
    #pragma unroll
    for (int i = 0; i < 4; ++i) {
        const int row = b * 16 + wv * 4 + i;
        const float* lr = logits + (size_t)row * N_CLS;
        float a  = (ln < N_CLS) ? lr[ln] : -INFINITY;
        float a2 = (ln + 64 < N_CLS) ? lr[ln + 64] : -INFINITY;
        float m = fmaxf(a, a2);
        #pragma unroll
        for (int off = 32; off; off >>= 1) m = fmaxf(m, __shfl_down(m, off));
        m = __shfl(m, 0);
        float e = 0.f;
        if (ln < N_CLS) e += expf(a - m);
        if (ln + 64 < N_CLS) e += expf(a2 - m);
        #pragma unroll
        for (int off = 32; off; off >>= 1) e += __shfl_down(e, off);
        if (ln == 0) {
            float lsm = m + logf(e);
            int lbl = labels[row];
            const float* sel = boxreg + (size_t)row * (4 * N_CLS) + lbl * 4;
            const float* tg = tgt + (size_t)row * 4;
            float s = 0.f;
            #pragma unroll
            for (int j = 0; j < 4; ++j) {
                float d = sel[j] - tg[j];
                float ad = fabsf(d);
                s += (ad < SMOOTH_BETA) ? (0.5f * d * d / SMOOTH_BETA)
                                        : (ad - 0.5f * SMOOTH_BETA);
            }
            csum += lsm - lr[lbl];
            if (lbl > 0) bsum += s;
        }
    }
    if (ln == 0) { s_red_v[wv] = csum; s_red_i[wv] = __float_as_int(bsum); }
    __syncthreads();
    if (tid == 0) {
        float c  = s_red_v[0] + s_red_v[1] + s_red_v[2] + s_red_v[3];
        float bx = __int_as_float(s_red_i[0]) + __int_as_float(s_red_i[1])
                 + __int_as_float(s_red_i[2]) + __int_as_float(s_red_i[3]);
        ws[b * 2]     = c;
        ws[b * 2 + 1] = bx;
    }
}

// Tiny finisher: reduce 256 loss partial pairs -> out[0], out[1].
__global__ __launch_bounds__(256) void loss_finish(
    const float* __restrict__ ws, float* __restrict__ out)
{
    __shared__ float s_c[4], s_b[4];
    const int tid = threadIdx.x, wv = tid >> 6, ln = tid & 63;
    float c = ws[tid * 2];
    float b = ws[tid * 2 + 1];
    #pragma unroll
    for (int off = 32; off; off >>= 1) {
        c += __shfl_down(c, off);
        b += __shfl_down(b, off);
    }
    if (ln == 0) { s_c[wv] = c; s_b[wv] = b; }
    __syncthreads();
    if (tid == 0) {
        float cc = s_c[0] + s_c[1] + s_c[2] + s_c[3];
        float bb = s_b[0] + s_b[1] + s_b[2] + s_b[3];
        out[0] = cc * (1.f / (float)N_ROWS);
        out[1] = bb * (1.f / (float)N_ROWS);
    }
}

extern "C" void kernel_launch(void* const* d_in, const int* in_sizes, int n_in,
                              void* d_out, int out_size, void* d_ws, size_t ws_size,
                              hipStream_t stream) {
    const float* class_logits = (const float*)d_in[0];
    const float* box_regression = (const float*)d_in[1];
    const int*   labels = (const int*)d_in[2];
    const float* regression_targets = (const float*)d_in[3];
    const float* kp_maps = (const float*)d_in[4];
    const float* kp_rois = (const float*)d_in[5];
    const float* mask_logits = (const float*)d_in[6];
    const int*   mask_labels = (const int*)d_in[7];
    float* out = (float*)d_out;
    float* ws  = (float*)d_ws;

    fused_kernel<<<TOTAL_BLOCKS, 256, 0, stream>>>(
        kp_maps, kp_rois, class_logits, box_regression, labels,
        regression_targets, mask_logits, mask_labels, out, ws);
    loss_finish<<<1, 256, 0, stream>>>(ws, out);
}

// Round 5
// 471.935 us; speedup vs baseline: 1.1424x; 1.0368x over previous
//
#include <hip/hip_runtime.h>
#include <math.h>
#include <stdint.h>

#define RES 64
#define IN_HW 56
#define K_KP 17
#define N_ROWS 4096
#define N_CLS 91
#define R_ROIS 1024
#define SMOOTH_BETA (1.0f / 9.0f)

#define KP_BLOCKS (R_ROIS * K_KP)          /* 17408 */
#define LOSS_BLOCKS 256                    /* 16 rows per block */
#define MASK_START (KP_BLOCKS + LOSS_BLOCKS)
#define TOTAL_BLOCKS (MASK_START + R_ROIS) /* 18688 */

// Output layout (fp32 flat):
//   [0]                      cls_loss
//   [1]                      box_loss
//   [2 .. 2+52224)           xy_preds  (1024,17,3)
//   [52226 .. 52226+17408)   end_scores (1024,17)
//   [69634 .. 69634+802816)  mask_prob (1024,1,28,28)

// floor((7*o - 0.5)/8) == (7*o - 1) >> 3 for integer o >= 0 (arith shift)
__device__ __host__ constexpr int fl_of(int o) { return (7 * o - 1) >> 3; }
// clamped 4-tap base row/col for output index o (always in [0, 52])
__device__ __host__ constexpr int base_of(int o) {
    int f = fl_of(o) - 1;
    return f < 0 ? 0 : (f > IN_HW - 4 ? IN_HW - 4 : f);
}

// ---- compile-time bicubic weight table (JAX: half-pixel centers, Keys a=-0.5,
// OOR taps dropped + renorm), BASE-ALIGNED: output o uses inputs
// base_of(o)..base_of(o)+3 with weights g_wtab.v[o]. ----
struct alignas(16) CW4 { float x, y, z, w; };
struct WTab { CW4 v[RES]; };

constexpr WTab make_wtab() {
    WTab t{};
    for (int o = 0; o < RES; ++o) {
        float s = (o + 0.5f) * 0.875f - 0.5f;   // exact scale 56/64
        int fl = fl_of(o);
        float w[4] = {}; float wsum = 0.f;
        for (int k = 0; k < 4; ++k) {
            int i = fl - 1 + k;
            float x = s - (float)i;
            x = x < 0.f ? -x : x;               // Keys cubic, a = -0.5
            float wv = x < 1.f ? ((1.5f * x - 2.5f) * x) * x + 1.f
                     : (x < 2.f ? ((-0.5f * x + 2.5f) * x - 4.f) * x + 2.f : 0.f);
            if (i < 0 || i >= IN_HW) wv = 0.f;
            w[k] = wv; wsum += wv;
        }
        const int fm1 = fl - 1;
        const int base = fm1 < 0 ? 0 : (fm1 > IN_HW - 4 ? IN_HW - 4 : fm1);
        const int sh = fm1 - base;              // in [-2, 2]
        const float inv = 1.0f / wsum;
        float wa[4] = {};
        for (int j = 0; j < 4; ++j) {
            int k = j - sh;
            if (k >= 0 && k < 4) wa[j] = w[k] * inv;
        }
        t.v[o] = CW4{wa[0], wa[1], wa[2], wa[3]};
    }
    return t;
}
static __constant__ WTab g_wtab = make_wtab();

#define GLB_AS __attribute__((address_space(1)))
#define LDS_AS __attribute__((address_space(3)))
__device__ __forceinline__ void gload_lds16(const void* g, void* l) {
    __builtin_amdgcn_global_load_lds((const GLB_AS uint32_t*)g,
                                     (LDS_AS uint32_t*)l, 16, 0, 0);
}
__device__ __forceinline__ void gload_lds4(const void* g, void* l) {
    __builtin_amdgcn_global_load_lds((const GLB_AS uint32_t*)g,
                                     (LDS_AS uint32_t*)l, 4, 0, 0);
}

// One launch for everything:
//   blocks [0, 17408)        : keypoint bicubic 56->64 + argmax (1 block per (r,k))
//   blocks [17408, 17664)    : fastrcnn losses, 16 rows/block, partials -> ws
//   blocks [17664, 18688)    : mask sigmoid gather (1 block per roi)
__global__ __launch_bounds__(256) void fused_kernel(
    const float* __restrict__ maps, const float* __restrict__ rois,
    const float* __restrict__ logits, const float* __restrict__ boxreg,
    const int* __restrict__ labels, const float* __restrict__ tgt,
    const float* __restrict__ ml, const int* __restrict__ mlab,
    float* __restrict__ out, float* __restrict__ ws)
{
    __shared__ float sm_in[IN_HW * IN_HW];    // 3136 f = 12544 B
    __shared__ float s_red_v[4];
    __shared__ int   s_red_i[4];

    const int bid = blockIdx.x;
    const int tid = threadIdx.x;
    const int wv = tid >> 6, ln = tid & 63;

    if (bid < KP_BLOCKS) {
        // ---------------- keypoints: bicubic 56->64 + argmax, FUSED H+V ----------------
        const int map_id = bid;               // r*17 + k

        // stage 56x56 map directly into LDS (wave-uniform base + lane*16, linear)
        {
            const char* gb = (const char*)(maps + (size_t)map_id * (IN_HW * IN_HW));
            char* lb = (char*)sm_in;
            #pragma unroll
            for (int j = 0; j < 3; ++j) {
                const int o = ((j * 4 + wv) * 64 + ln) * 16;
                gload_lds16(gb + o, lb + o);
            }
            if (wv == 0) {
                const int o = 12288 + ln * 4;
                gload_lds4(gb + o, lb + o);
            }
        }
        __syncthreads();

        // Fused pass: lane = ox, wave owns 16 consecutive oy. Horizontal-pass rows
        // are computed ON DEMAND into a 4-row vertical register window. H weights
        // come from the constant table via VMEM (lane-indexed, L1-hot); V weights
        // via SMEM s_load (wave-uniform index) -> SGPR operands, zero DS/VALU cost.
        float best = -INFINITY; int bidx = 0;
        {
            const int ox = ln;
            const int hbase = base_of(ox);                   // per-lane, hoisted
            const CW4 hw = g_wtab.v[ox];                     // global_load_dwordx4
            const float* hp = sm_in + hbase;

            auto hrow = [&](int yy) -> float {
                const float* p = hp + yy * IN_HW;
                return hw.x * p[0] + hw.y * p[1] + hw.z * p[2] + hw.w * p[3];
            };

            const int oy0u = __builtin_amdgcn_readfirstlane(wv * 16);
            int base = base_of(oy0u);
            float r0 = hrow(base);
            float r1 = hrow(base + 1);
            float r2 = hrow(base + 2);
            float r3 = hrow(base + 3);
            #pragma unroll
            for (int k = 0; k < 16; ++k) {
                const int oy = oy0u + k;
                const CW4 w = g_wtab.v[oy];                  // s_load_dwordx4 (uniform)
                float v = w.x * r0 + w.y * r1 + w.z * r2 + w.w * r3;
                if (v > best) { best = v; bidx = oy * RES + ox; }
                if (k < 15) {
                    const int nb = base_of(oy + 1);          // wave-uniform SALU
                    if (nb != base) {
                        r0 = r1; r1 = r2; r2 = r3;
                        r3 = hrow(nb + 3);
                        base = nb;
                    }
                }
            }
        }
        // two-phase wave reduce: value-max, then min index among ties
        float wmax = best;
        #pragma unroll
        for (int off = 32; off; off >>= 1) wmax = fmaxf(wmax, __shfl_xor(wmax, off));
        int cand = (best == wmax) ? bidx : 0x7FFFFFFF;
        #pragma unroll
        for (int off = 32; off; off >>= 1) cand = min(cand, __shfl_xor(cand, off));

        if (ln == 0) { s_red_v[wv] = wmax; s_red_i[wv] = cand; }
        __syncthreads();
        if (tid == 0) {
            float bv = s_red_v[0]; int bi = s_red_i[0];
            #pragma unroll
            for (int w = 1; w < 4; ++w) {
                float v = s_red_v[w]; int i2 = s_red_i[w];
                if (v > bv || (v == bv && i2 < bi)) { bv = v; bi = i2; }
            }
            const int r = map_id / K_KP;
            const float x0 = rois[r * 4 + 0], y0r = rois[r * 4 + 1];
            const float x1 = rois[r * 4 + 2], y1r = rois[r * 4 + 3];
            const float wdt = fmaxf(x1 - x0, 1.f), hgt = fmaxf(y1r - y0r, 1.f);
            const float wc = wdt * (1.f / 64.f), hc = hgt * (1.f / 64.f);
            const int xi = bi & 63, yi = bi >> 6;
            float* xyp = out + 2 + (size_t)map_id * 3;
            xyp[0] = ((float)xi + 0.5f) * wc + x0;
            xyp[1] = ((float)yi + 0.5f) * hc + y0r;
            xyp[2] = 1.f;
            out[52226 + map_id] = bv;
        }
        return;
    }

    if (bid >= MASK_START) {
        // ------------- mask: gather selected class, sigmoid, write -------------
        const int r = bid - MASK_START;
        const int lbl = mlab[r];
        const float2* src = (const float2*)(ml + ((size_t)r * N_CLS + lbl) * 784);
        float2* dst = (float2*)(out + 69634 + (size_t)r * 784);
        for (int i = tid; i < 392; i += 256) {
            float2 v = src[i];
            float2 o;
            o.x = 1.f / (1.f + expf(-v.x));
            o.y = 1.f / (1.f + expf(-v.y));
            dst[i] = o;
        }
        return;
    }

    // ---------------- losses: 16 rows/block, deterministic partials to ws ----------------
    const int b = bid - KP_BLOCKS;            // 0..255
    float csum = 0.f, bsum = 0.f;
    #pragma unroll
    for (int i = 0; i < 4; ++i) {
        const int row = b * 16 + wv * 4 + i;
        const float* lr = logits + (size_t)row * N_CLS;
        float a  = (ln < N_CLS) ? lr[ln] : -INFINITY;
        float a2 = (ln + 64 < N_CLS) ? lr[ln + 64] : -INFINITY;
        float m = fmaxf(a, a2);
        #pragma unroll
        for (int off = 32; off; off >>= 1) m = fmaxf(m, __shfl_down(m, off));
        m = __shfl(m, 0);
        float e = 0.f;
        if (ln < N_CLS) e += expf(a - m);
        if (ln + 64 < N_CLS) e += expf(a2 - m);
        #pragma unroll
        for (int off = 32; off; off >>= 1) e += __shfl_down(e, off);
        if (ln == 0) {
            float lsm = m + logf(e);
            int lbl = labels[row];
            const float* sel = boxreg + (size_t)row * (4 * N_CLS) + lbl * 4;
            const float* tg = tgt + (size_t)row * 4;
            float s = 0.f;
            #pragma unroll
            for (int j = 0; j < 4; ++j) {
                float d = sel[j] - tg[j];
                float ad = fabsf(d);
                s += (ad < SMOOTH_BETA) ? (0.5f * d * d / SMOOTH_BETA)
                                        : (ad - 0.5f * SMOOTH_BETA);
            }
            csum += lsm - lr[lbl];
            if (lbl > 0) bsum += s;
        }
    }
    if (ln == 0) { s_red_v[wv] = csum; s_red_i[wv] = __float_as_int(bsum); }
    __syncthreads();
    if (tid == 0) {
        float c  = s_red_v[0] + s_red_v[1] + s_red_v[2] + s_red_v[3];
        float bx = __int_as_float(s_red_i[0]) + __int_as_float(s_red_i[1])
                 + __int_as_float(s_red_i[2]) + __int_as_float(s_red_i[3]);
        ws[b * 2]     = c;
        ws[b * 2 + 1] = bx;
    }
}

// Tiny finisher: reduce 256 loss partial pairs -> out[0], out[1].
__global__ __launch_bounds__(256) void loss_finish(
    const float* __restrict__ ws, float* __restrict__ out)
{
    __shared__ float s_c[4], s_b[4];
    const int tid = threadIdx.x, wv = tid >> 6, ln = tid & 63;
    float c = ws[tid * 2];
    float b = ws[tid * 2 + 1];
    #pragma unroll
    for (int off = 32; off; off >>= 1) {
        c += __shfl_down(c, off);
        b += __shfl_down(b, off);
    }
    if (ln == 0) { s_c[wv] = c; s_b[wv] = b; }
    __syncthreads();
    if (tid == 0) {
        float cc = s_c[0] + s_c[1] + s_c[2] + s_c[3];
        float bb = s_b[0] + s_b[1] + s_b[2] + s_b[3];
        out[0] = cc * (1.f / (float)N_ROWS);
        out[1] = bb * (1.f / (float)N_ROWS);
    }
}

extern "C" void kernel_launch(void* const* d_in, const int* in_sizes, int n_in,
                              void* d_out, int out_size, void* d_ws, size_t ws_size,
                              hipStream_t stream) {
    const float* class_logits = (const float*)d_in[0];
    const float* box_regression = (const float*)d_in[1];
    const int*   labels = (const int*)d_in[2];
    const float* regression_targets = (const float*)d_in[3];
    const float* kp_maps = (const float*)d_in[4];
    const float* kp_rois = (const float*)d_in[5];
    const float* mask_logits = (const float*)d_in[6];
    const int*   mask_labels = (const int*)d_in[7];
    float* out = (float*)d_out;
    float* ws  = (float*)d_ws;

    fused_kernel<<<TOTAL_BLOCKS, 256, 0, stream>>>(
        kp_maps, kp_rois, class_logits, box_regression, labels,
        regression_targets, mask_logits, mask_labels, out, ws);
    loss_finish<<<1, 256, 0, stream>>>(ws, out);
}